// Round 19
// baseline (112.777 us; speedup 1.0000x reference)
//
#include <hip/hip_runtime.h>
#include <cstdint>
#include <cstddef>

#define LNUM 8
#define NTOK 8192
#define HDIM 768
#define IDIM 1536

typedef __bf16 bf16x8 __attribute__((ext_vector_type(8)));
typedef float f32x4 __attribute__((ext_vector_type(4)));

__device__ __forceinline__ void gload16(void* lds, const void* gsrc) {
  __builtin_amdgcn_global_load_lds(
      (const __attribute__((address_space(1))) void*)gsrc,
      (__attribute__((address_space(3))) void*)lds, 16, 0, 0);
}

// fast GELU: x * sigmoid(2u), u = 0.79788456*(x + 0.044715 x^3)
__device__ __forceinline__ float gelu_f(float x) {
  float xx = x * x;
  float u = x * __builtin_fmaf(0.0356774081f, xx, 0.7978845608f);
  float t = __builtin_exp2f(-2.8853900817779268f * u);  // e^{-2u}
  return x * __builtin_amdgcn_rcpf(1.0f + t);
}

// meta ints: [0..8] = expert offsets
// transpose+convert one 64x64 tile: dst[C][R] (bf16) <- src[R][C] (f32)
__device__ __forceinline__ void tr_cvt_tile(float (*tile)[65], const float* src,
                                            __bf16* dst, int R, int C, int r0,
                                            int c0, int t) {
  int rr = t >> 4, cc = (t & 15) << 2;
  #pragma unroll
  for (int it = 0; it < 4; ++it) {
    float4 v = *(const float4*)&src[(size_t)(r0 + rr + it * 16) * C + c0 + cc];
    tile[rr + it * 16][cc] = v.x;
    tile[rr + it * 16][cc + 1] = v.y;
    tile[rr + it * 16][cc + 2] = v.z;
    tile[rr + it * 16][cc + 3] = v.w;
  }
  __syncthreads();
  int c = t >> 2, rcb = (t & 3) << 3;
  #pragma unroll
  for (int it = 0; it < 2; ++it) {
    int r = rcb + it * 32;
    bf16x8 o;
    #pragma unroll
    for (int j = 0; j < 8; ++j) o[j] = (__bf16)tile[r + j][c];
    *(bf16x8*)&dst[(size_t)(c0 + c) * R + r0 + r] = o;
  }
}

// K1 prep: [0,32) scatter (self-hist; block 0 writes offs),
// [32,2336) w1 transpose (XCD-affine: e = idx&7). conv_z eliminated —
// gemm1 converts A in-register; gemm2 residual reads f32 z directly.
#define NB_SC 32
#define NB_W 2304
__global__ __launch_bounds__(256) void prep_kernel(
    const int* __restrict__ lid, const float* __restrict__ w1,
    int* __restrict__ meta, int* __restrict__ perm, __bf16* __restrict__ w1t) {
  __shared__ float tile[64][65];
  int bxid = blockIdx.x;
  int tid = threadIdx.x;
  if (bxid < NB_SC) {
    __shared__ int ctw[4][LNUM], cbw[4][LNUM];
    __shared__ int lcnt[LNUM], lbase[LNUM];
    int b = bxid, wv = tid >> 6;
    if (tid < 32) {
      ctw[tid >> 3][tid & 7] = 0;
      cbw[tid >> 3][tid & 7] = 0;
    }
    if (tid < LNUM) lcnt[tid] = 0;
    __syncthreads();
    int cut = b << 8;
    for (int i = tid; i < NTOK; i += 256) {
      int e = lid[i];
      atomicAdd(&ctw[wv][e], 1);
      if (i < cut) atomicAdd(&cbw[wv][e], 1);
    }
    __syncthreads();
    if (tid < LNUM) {
      int e = tid, o = 0;
      for (int e2 = 0; e2 < LNUM; ++e2) {
        int s = ctw[0][e2] + ctw[1][e2] + ctw[2][e2] + ctw[3][e2];
        if (e2 < e) o += s;
      }
      lbase[e] = o + cbw[0][e] + cbw[1][e] + cbw[2][e] + cbw[3][e];
    }
    if (b == 0 && tid == 0) {
      int o = 0;
      for (int e2 = 0; e2 < LNUM; ++e2) {
        int s = ctw[0][e2] + ctw[1][e2] + ctw[2][e2] + ctw[3][e2];
        meta[e2] = o;
        o += s;
      }
      meta[8] = o;
    }
    __syncthreads();
    int i = (b << 8) + tid;
    int e = lid[i];
    int r = atomicAdd(&lcnt[e], 1);
    perm[lbase[e] + r] = i;
  } else {
    int idx = bxid - NB_SC;
    int e = idx & 7, rem = idx >> 3;
    int c0 = (rem % 24) * 64, r0 = (rem / 24) * 64;
    tr_cvt_tile(tile, w1 + (size_t)e * HDIM * IDIM, w1t + (size_t)e * HDIM * IDIM,
                HDIM, IDIM, r0, c0, tid);
  }
}

// ---------------- K2: gemm1 (blocks [0,576)) + w2 transpose ([576,1728)) ----
// gemm1: act = gelu(z[perm] @ w1t^T + b1). Tile 128M x 256N, BK=64,
// single-buffer, 8 waves (2M x 4N, wave-tile 64x64). Expert-XCD: e = bid & 7.
// A is REG-STAGED from f32 z with T14 async split: issue av(kk+1) AFTER
// barrier1 so the MFMA phase covers the L2 latency; cvt+ds_write next iter.
// LDS swizzle Ls[r][c] = G[r][c ^ ((r&7)<<3)] on both paths.
// w2t tail: 2 tiles per block (512 threads, two LDS tiles).
#define G1GRID 576
#define NB_W2 1152
__global__ __launch_bounds__(512) void gemm1_kernel(
    const float* __restrict__ z, const __bf16* __restrict__ w1t,
    const float* __restrict__ b1, const int* __restrict__ meta,
    const int* __restrict__ perm, __bf16* __restrict__ act,
    const float* __restrict__ w2, __bf16* __restrict__ w2t) {
  __shared__ __align__(16) char smem[49152];
  int bid = blockIdx.x;
  int tid = threadIdx.x;
  if (bid >= G1GRID) {
    // ---- w2 [I][H] -> w2t [H][I], XCD-affine (b&7 = XCD = expert) ----
    int b = bid - G1GRID;               // 0..1151
    int s = tid >> 8;                   // half-block 0/1
    int t = tid & 255;
    float (*tile)[65] = (float (*)[65])(smem + s * 16640);
    int e = b & 7;
    int rem2 = ((b >> 3) << 1) + s;     // 0..287 per expert
    int c0 = (rem2 % 12) * 64, r0 = (rem2 / 12) * 64;
    tr_cvt_tile(tile, w2 + (size_t)e * HDIM * IDIM, w2t + (size_t)e * HDIM * IDIM,
                IDIM, HDIM, r0, c0, t);
    return;
  }
  __bf16* As = (__bf16*)smem;              // [128][64]
  __bf16* Bs = (__bf16*)(smem + 16384);    // [256][64]
  const int* offs = meta;
  int e = bid & 7;                          // expert == XCD
  int r = bid >> 3;                         // 0..71
  int mt = r / 6, nt = r % 6;
  int off0 = offs[e];
  int cnt = offs[e + 1] - off0;
  if ((mt << 7) >= cnt) return;
  int row0 = off0 + (mt << 7);
  int cntRem = cnt - (mt << 7);
  if (cntRem > 128) cntRem = 128;
  int n0 = nt << 8;
  int lane = tid & 63, wv = tid >> 6;
  int wr = wv >> 2, wc = wv & 3;            // 2M x 4N
  int swz = ((lane & 7) ^ (lane >> 3)) << 3;  // pre-swizzled elem offset

  const float* srcAf0;
  const float* srcAf1;
  {
    int row = ((wv * 2 + 0) << 3) + (lane >> 3);
    int rA = row < cntRem ? row : cntRem - 1;
    srcAf0 = z + (size_t)perm[row0 + rA] * HDIM + swz;
    row = ((wv * 2 + 1) << 3) + (lane >> 3);
    rA = row < cntRem ? row : cntRem - 1;
    srcAf1 = z + (size_t)perm[row0 + rA] * HDIM + swz;
  }
  const __bf16* srcB[4];
  #pragma unroll
  for (int i = 0; i < 4; ++i) {
    int row = ((wv * 4 + i) << 3) + (lane >> 3);   // 32 B-rows per wave
    srcB[i] = w1t + ((size_t)e * IDIM + n0 + row) * HDIM + swz;
  }

  int rswz = (lane & 7) << 3;
  f32x4 acc[4][4] = {};

  const int NT = HDIM / 64;  // 12
  // prologue: load av for kk=0 (named regs, rule #20)
  float4 av0 = *(const float4*)srcAf0;
  float4 av1 = *(const float4*)(srcAf0 + 4);
  float4 av2 = *(const float4*)srcAf1;
  float4 av3 = *(const float4*)(srcAf1 + 4);

  for (int kk = 0; kk < NT; ++kk) {
    // stage B async first (latency overlaps the cvt ALU work)
    #pragma unroll
    for (int i = 0; i < 4; ++i)
      gload16(Bs + ((wv * 4 + i) << 9), srcB[i] + kk * 64);
    // cvt current av -> swizzled As write
    {
      bf16x8 o0, o1;
      #pragma unroll
      for (int j = 0; j < 4; ++j) {
        o0[j] = (__bf16)av0[j];
        o0[j + 4] = (__bf16)av1[j];
        o1[j] = (__bf16)av2[j];
        o1[j + 4] = (__bf16)av3[j];
      }
      *(bf16x8*)((char*)As + ((wv * 2 + 0) << 10) + lane * 16) = o0;
      *(bf16x8*)((char*)As + ((wv * 2 + 1) << 10) + lane * 16) = o1;
    }
    __syncthreads();  // drains B staging (vmcnt0) + As writes (lgkm)
    // T14: issue next av NOW — MFMA phase below covers the latency
    if (kk + 1 < NT) {
      const float* s0 = srcAf0 + (kk + 1) * 64;
      const float* s1 = srcAf1 + (kk + 1) * 64;
      av0 = *(const float4*)s0;
      av1 = *(const float4*)(s0 + 4);
      av2 = *(const float4*)s1;
      av3 = *(const float4*)(s1 + 4);
    }
    #pragma unroll
    for (int k2 = 0; k2 < 2; ++k2) {
      int kb = (k2 * 32 + ((lane >> 4) << 3)) ^ rswz;
      bf16x8 a[4], b[4];
      #pragma unroll
      for (int mi = 0; mi < 4; ++mi)
        a[mi] = *(const bf16x8*)&As[((wr * 64 + mi * 16 + (lane & 15)) << 6) + kb];
      #pragma unroll
      for (int ni = 0; ni < 4; ++ni)
        b[ni] = *(const bf16x8*)&Bs[((wc * 64 + ni * 16 + (lane & 15)) << 6) + kb];
      #pragma unroll
      for (int mi = 0; mi < 4; ++mi)
        #pragma unroll
        for (int ni = 0; ni < 4; ++ni)
          acc[mi][ni] = __builtin_amdgcn_mfma_f32_16x16x32_bf16(a[mi], b[ni], acc[mi][ni], 0, 0, 0);
    }
    __syncthreads();  // av(kk+1) loads have had the whole MFMA phase
  }

  float bb[4];
  #pragma unroll
  for (int ni = 0; ni < 4; ++ni)
    bb[ni] = b1[e * IDIM + n0 + wc * 64 + ni * 16 + (lane & 15)];

  #pragma unroll
  for (int mi = 0; mi < 4; ++mi) {
    int gr0 = wr * 64 + mi * 16 + ((lane >> 4) << 2);
    #pragma unroll
    for (int r2 = 0; r2 < 4; ++r2) {
      int g = gr0 + r2;
      if (g < cntRem) {
        size_t p = (size_t)(row0 + g);
        #pragma unroll
        for (int ni = 0; ni < 4; ++ni) {
          int col = n0 + wc * 64 + ni * 16 + (lane & 15);
          act[p * IDIM + col] = (__bf16)gelu_f(acc[mi][ni][r2] + bb[ni]);
        }
      }
    }
  }
}

// ---------------- K3 gemm2: out[tok] = z[tok] + act @ w2t^T + b2 --------------
// Tile 128x128, BK=64, single-buffer, 8 waves. Expert-XCD affinity: e = bid&7.
#define G2GRID 576
__global__ __launch_bounds__(512) void gemm2_kernel(
    const __bf16* __restrict__ act, const __bf16* __restrict__ w2t,
    const float* __restrict__ b2, const float* __restrict__ z,
    const int* __restrict__ meta, const int* __restrict__ perm,
    float* __restrict__ out) {
  __shared__ __align__(16) char smem[32768];
  __bf16* As = (__bf16*)smem;              // [128][64]
  __bf16* Bs = (__bf16*)(smem + 16384);    // [128][64]
  const int* offs = meta;
  int bid = blockIdx.x;
  int e = bid & 7;
  int r = bid >> 3;                         // 0..71
  int mt = r / 6, nt = r % 6;
  int off0 = offs[e];
  int cnt = offs[e + 1] - off0;
  if ((mt << 7) >= cnt) return;
  int row0 = off0 + (mt << 7);
  int cntRem = cnt - (mt << 7);
  if (cntRem > 128) cntRem = 128;
  int n0 = nt << 7;
  int tid = threadIdx.x, lane = tid & 63, wv = tid >> 6;
  int wr = wv >> 2, wc = wv & 3;
  int swz = ((lane & 7) ^ (lane >> 3)) << 3;

  const __bf16* srcA[2];
  const __bf16* srcB[2];
  #pragma unroll
  for (int i = 0; i < 2; ++i) {
    int row = ((wv * 2 + i) << 3) + (lane >> 3);
    int rA = row < cntRem ? row : cntRem - 1;
    srcA[i] = act + (size_t)(row0 + rA) * IDIM + swz;
    srcB[i] = w2t + ((size_t)e * HDIM + n0 + row) * IDIM + swz;
  }

  int rswz = (lane & 7) << 3;
  f32x4 acc[4][2] = {};

  for (int kk = 0; kk < IDIM / 64; ++kk) {
    #pragma unroll
    for (int i = 0; i < 2; ++i) {
      gload16(As + ((wv * 2 + i) << 9), srcA[i] + kk * 64);
      gload16(Bs + ((wv * 2 + i) << 9), srcB[i] + kk * 64);
    }
    __syncthreads();
    #pragma unroll
    for (int k2 = 0; k2 < 2; ++k2) {
      int kb = (k2 * 32 + ((lane >> 4) << 3)) ^ rswz;
      bf16x8 a[4], b[2];
      #pragma unroll
      for (int mi = 0; mi < 4; ++mi)
        a[mi] = *(const bf16x8*)&As[((wr * 64 + mi * 16 + (lane & 15)) << 6) + kb];
      #pragma unroll
      for (int ni = 0; ni < 2; ++ni)
        b[ni] = *(const bf16x8*)&Bs[((wc * 32 + ni * 16 + (lane & 15)) << 6) + kb];
      #pragma unroll
      for (int mi = 0; mi < 4; ++mi)
        #pragma unroll
        for (int ni = 0; ni < 2; ++ni)
          acc[mi][ni] = __builtin_amdgcn_mfma_f32_16x16x32_bf16(a[mi], b[ni], acc[mi][ni], 0, 0, 0);
    }
    __syncthreads();
  }

  float bb[2];
  #pragma unroll
  for (int ni = 0; ni < 2; ++ni)
    bb[ni] = b2[e * HDIM + n0 + wc * 32 + ni * 16 + (lane & 15)];

  #pragma unroll
  for (int mi = 0; mi < 4; ++mi) {
    int gr0 = wr * 64 + mi * 16 + ((lane >> 4) << 2);
    #pragma unroll
    for (int r2 = 0; r2 < 4; ++r2) {
      int g = gr0 + r2;
      if (g < cntRem) {
        int p = row0 + g;
        int tok = perm[p];
        #pragma unroll
        for (int ni = 0; ni < 2; ++ni) {
          int col = n0 + wc * 32 + ni * 16 + (lane & 15);
          out[(size_t)tok * HDIM + col] =
              z[(size_t)tok * HDIM + col] + acc[mi][ni][r2] + bb[ni];
        }
      }
    }
  }
}

extern "C" void kernel_launch(void* const* d_in, const int* in_sizes, int n_in,
                              void* d_out, int out_size, void* d_ws, size_t ws_size,
                              hipStream_t stream) {
  const float* z  = (const float*)d_in[0];
  const int*   lid = (const int*)d_in[1];
  const float* w1 = (const float*)d_in[2];
  const float* b1 = (const float*)d_in[3];
  const float* w2 = (const float*)d_in[4];
  const float* b2 = (const float*)d_in[5];
  float* out = (float*)d_out;
  char* ws = (char*)d_ws;

  int* meta = (int*)ws;                     // 9 ints
  int* perm = (int*)(ws + 2048);            // NTOK ints
  __bf16* w1t = (__bf16*)(ws + 2048 + 32768);
  __bf16* w2t = w1t + (size_t)LNUM * HDIM * IDIM;
  __bf16* act = w2t + (size_t)LNUM * HDIM * IDIM;

  prep_kernel<<<NB_SC + NB_W, 256, 0, stream>>>(lid, w1, meta, perm, w1t);
  gemm1_kernel<<<G1GRID + NB_W2, 512, 0, stream>>>(z, w1t, b1, meta, perm, act,
                                                   w2, w2t);
  gemm2_kernel<<<G2GRID, 512, 0, stream>>>(act, w2t, b2, z, meta, perm, out);
}

// Round 20
// 89.588 us; speedup vs baseline: 1.2588x; 1.2588x over previous
//
#include <hip/hip_runtime.h>
#include <cstdint>
#include <cstddef>

#define LNUM 8
#define NTOK 8192
#define HDIM 768
#define IDIM 1536

typedef __bf16 bf16x8 __attribute__((ext_vector_type(8)));
typedef float f32x4 __attribute__((ext_vector_type(4)));

__device__ __forceinline__ void gload16(void* lds, const void* gsrc) {
  __builtin_amdgcn_global_load_lds(
      (const __attribute__((address_space(1))) void*)gsrc,
      (__attribute__((address_space(3))) void*)lds, 16, 0, 0);
}

// fast GELU: x * sigmoid(2u), u = 0.79788456*(x + 0.044715 x^3)
__device__ __forceinline__ float gelu_f(float x) {
  float xx = x * x;
  float u = x * __builtin_fmaf(0.0356774081f, xx, 0.7978845608f);
  float t = __builtin_exp2f(-2.8853900817779268f * u);  // e^{-2u}
  return x * __builtin_amdgcn_rcpf(1.0f + t);
}

// meta ints: [0..8] = expert offsets
// transpose+convert one 64x64 tile: dst[C][R] (bf16) <- src[R][C] (f32)
__device__ __forceinline__ void tr_cvt_tile(float (*tile)[65], const float* src,
                                            __bf16* dst, int R, int C, int r0,
                                            int c0, int t) {
  int rr = t >> 4, cc = (t & 15) << 2;
  #pragma unroll
  for (int it = 0; it < 4; ++it) {
    float4 v = *(const float4*)&src[(size_t)(r0 + rr + it * 16) * C + c0 + cc];
    tile[rr + it * 16][cc] = v.x;
    tile[rr + it * 16][cc + 1] = v.y;
    tile[rr + it * 16][cc + 2] = v.z;
    tile[rr + it * 16][cc + 3] = v.w;
  }
  __syncthreads();
  int c = t >> 2, rcb = (t & 3) << 3;
  #pragma unroll
  for (int it = 0; it < 2; ++it) {
    int r = rcb + it * 32;
    bf16x8 o;
    #pragma unroll
    for (int j = 0; j < 8; ++j) o[j] = (__bf16)tile[r + j][c];
    *(bf16x8*)&dst[(size_t)(c0 + c) * R + r0 + r] = o;
  }
}

// K1 prep: [0,32) scatter (self-hist; block 0 writes offs),
// [32,2336) w1 transpose (XCD-affine: e = idx&7). conv_z eliminated —
// gemm1 converts A in-register; gemm2 residual reads f32 z directly.
#define NB_SC 32
#define NB_W 2304
__global__ __launch_bounds__(256) void prep_kernel(
    const int* __restrict__ lid, const float* __restrict__ w1,
    int* __restrict__ meta, int* __restrict__ perm, __bf16* __restrict__ w1t) {
  __shared__ float tile[64][65];
  int bxid = blockIdx.x;
  int tid = threadIdx.x;
  if (bxid < NB_SC) {
    __shared__ int ctw[4][LNUM], cbw[4][LNUM];
    __shared__ int lcnt[LNUM], lbase[LNUM];
    int b = bxid, wv = tid >> 6;
    if (tid < 32) {
      ctw[tid >> 3][tid & 7] = 0;
      cbw[tid >> 3][tid & 7] = 0;
    }
    if (tid < LNUM) lcnt[tid] = 0;
    __syncthreads();
    int cut = b << 8;
    for (int i = tid; i < NTOK; i += 256) {
      int e = lid[i];
      atomicAdd(&ctw[wv][e], 1);
      if (i < cut) atomicAdd(&cbw[wv][e], 1);
    }
    __syncthreads();
    if (tid < LNUM) {
      int e = tid, o = 0;
      for (int e2 = 0; e2 < LNUM; ++e2) {
        int s = ctw[0][e2] + ctw[1][e2] + ctw[2][e2] + ctw[3][e2];
        if (e2 < e) o += s;
      }
      lbase[e] = o + cbw[0][e] + cbw[1][e] + cbw[2][e] + cbw[3][e];
    }
    if (b == 0 && tid == 0) {
      int o = 0;
      for (int e2 = 0; e2 < LNUM; ++e2) {
        int s = ctw[0][e2] + ctw[1][e2] + ctw[2][e2] + ctw[3][e2];
        meta[e2] = o;
        o += s;
      }
      meta[8] = o;
    }
    __syncthreads();
    int i = (b << 8) + tid;
    int e = lid[i];
    int r = atomicAdd(&lcnt[e], 1);
    perm[lbase[e] + r] = i;
  } else {
    int idx = bxid - NB_SC;
    int e = idx & 7, rem = idx >> 3;
    int c0 = (rem % 24) * 64, r0 = (rem / 24) * 64;
    tr_cvt_tile(tile, w1 + (size_t)e * HDIM * IDIM, w1t + (size_t)e * HDIM * IDIM,
                HDIM, IDIM, r0, c0, tid);
  }
}

// ---------------- K2: gemm1 (blocks [0,576)) + w2 transpose ([576,1728)) ----
// gemm1: act = gelu(z[perm] @ w1t^T + b1). Tile 128M x 256N, BK=64,
// single-buffer, 8 waves (2M x 4N, wave-tile 64x64). Expert-XCD: e = bid & 7.
// A is REG-STAGED from f32 z (gather via perm) with in-register cvt + swizzled
// ds_write; B staged via global_load_lds from bf16 w1t.
// LDS swizzle Ls[r][c] = G[r][c ^ ((r&7)<<3)] on both paths.
// w2t tail: 2 tiles per block (512 threads, two LDS tiles).
#define G1GRID 576
#define NB_W2 1152
__global__ __launch_bounds__(512) void gemm1_kernel(
    const float* __restrict__ z, const __bf16* __restrict__ w1t,
    const float* __restrict__ b1, const int* __restrict__ meta,
    const int* __restrict__ perm, __bf16* __restrict__ act,
    const float* __restrict__ w2, __bf16* __restrict__ w2t) {
  __shared__ __align__(16) char smem[49152];
  int bid = blockIdx.x;
  int tid = threadIdx.x;
  if (bid >= G1GRID) {
    // ---- w2 [I][H] -> w2t [H][I], XCD-affine (b&7 = XCD = expert) ----
    int b = bid - G1GRID;               // 0..1151
    int s = tid >> 8;                   // half-block 0/1
    int t = tid & 255;
    float (*tile)[65] = (float (*)[65])(smem + s * 16640);
    int e = b & 7;
    int rem2 = ((b >> 3) << 1) + s;     // 0..287 per expert
    int c0 = (rem2 % 12) * 64, r0 = (rem2 / 12) * 64;
    tr_cvt_tile(tile, w2 + (size_t)e * HDIM * IDIM, w2t + (size_t)e * HDIM * IDIM,
                IDIM, HDIM, r0, c0, t);
    return;
  }
  __bf16* As = (__bf16*)smem;              // [128][64]
  __bf16* Bs = (__bf16*)(smem + 16384);    // [256][64]
  const int* offs = meta;
  int e = bid & 7;                          // expert == XCD
  int r = bid >> 3;                         // 0..71
  int mt = r / 6, nt = r % 6;
  int off0 = offs[e];
  int cnt = offs[e + 1] - off0;
  if ((mt << 7) >= cnt) return;
  int row0 = off0 + (mt << 7);
  int cntRem = cnt - (mt << 7);
  if (cntRem > 128) cntRem = 128;
  int n0 = nt << 8;
  int lane = tid & 63, wv = tid >> 6;
  int wr = wv >> 2, wc = wv & 3;            // 2M x 4N
  int swz = ((lane & 7) ^ (lane >> 3)) << 3;  // pre-swizzled elem offset

  const float* srcAf[2];
  const __bf16* srcB[4];
  #pragma unroll
  for (int i = 0; i < 2; ++i) {
    int row = ((wv * 2 + i) << 3) + (lane >> 3);   // 16 A-rows per wave
    int rA = row < cntRem ? row : cntRem - 1;
    int tok = perm[row0 + rA];
    srcAf[i] = z + (size_t)tok * HDIM + swz;
  }
  #pragma unroll
  for (int i = 0; i < 4; ++i) {
    int row = ((wv * 4 + i) << 3) + (lane >> 3);   // 32 B-rows per wave
    srcB[i] = w1t + ((size_t)e * IDIM + n0 + row) * HDIM + swz;
  }

  int rswz = (lane & 7) << 3;
  f32x4 acc[4][4] = {};

  for (int kk = 0; kk < HDIM / 64; ++kk) {
    // A: reg-stage f32 (issue loads first so they overlap B's gload_lds)
    float4 av[2][2];
    #pragma unroll
    for (int i = 0; i < 2; ++i) {
      const float* s = srcAf[i] + kk * 64;
      av[i][0] = *(const float4*)s;
      av[i][1] = *(const float4*)(s + 4);
    }
    #pragma unroll
    for (int i = 0; i < 4; ++i)
      gload16(Bs + ((wv * 4 + i) << 9), srcB[i] + kk * 64);
    #pragma unroll
    for (int i = 0; i < 2; ++i) {
      bf16x8 o;
      #pragma unroll
      for (int j = 0; j < 4; ++j) {
        o[j] = (__bf16)av[i][0][j];
        o[j + 4] = (__bf16)av[i][1][j];
      }
      *(bf16x8*)((char*)As + ((wv * 2 + i) << 10) + lane * 16) = o;
    }
    __syncthreads();
    #pragma unroll
    for (int k2 = 0; k2 < 2; ++k2) {
      int kb = (k2 * 32 + ((lane >> 4) << 3)) ^ rswz;
      bf16x8 a[4], b[4];
      #pragma unroll
      for (int mi = 0; mi < 4; ++mi)
        a[mi] = *(const bf16x8*)&As[((wr * 64 + mi * 16 + (lane & 15)) << 6) + kb];
      #pragma unroll
      for (int ni = 0; ni < 4; ++ni)
        b[ni] = *(const bf16x8*)&Bs[((wc * 64 + ni * 16 + (lane & 15)) << 6) + kb];
      #pragma unroll
      for (int mi = 0; mi < 4; ++mi)
        #pragma unroll
        for (int ni = 0; ni < 4; ++ni)
          acc[mi][ni] = __builtin_amdgcn_mfma_f32_16x16x32_bf16(a[mi], b[ni], acc[mi][ni], 0, 0, 0);
    }
    __syncthreads();
  }

  float bb[4];
  #pragma unroll
  for (int ni = 0; ni < 4; ++ni)
    bb[ni] = b1[e * IDIM + n0 + wc * 64 + ni * 16 + (lane & 15)];

  #pragma unroll
  for (int mi = 0; mi < 4; ++mi) {
    int gr0 = wr * 64 + mi * 16 + ((lane >> 4) << 2);
    #pragma unroll
    for (int r2 = 0; r2 < 4; ++r2) {
      int g = gr0 + r2;
      if (g < cntRem) {
        size_t p = (size_t)(row0 + g);
        #pragma unroll
        for (int ni = 0; ni < 4; ++ni) {
          int col = n0 + wc * 64 + ni * 16 + (lane & 15);
          act[p * IDIM + col] = (__bf16)gelu_f(acc[mi][ni][r2] + bb[ni]);
        }
      }
    }
  }
}

// ---------------- K3 gemm2: out[tok] = z[tok] + act @ w2t^T + b2 --------------
// Tile 128x128, BK=64, single-buffer, 8 waves. Expert-XCD affinity: e = bid&7.
#define G2GRID 576
__global__ __launch_bounds__(512) void gemm2_kernel(
    const __bf16* __restrict__ act, const __bf16* __restrict__ w2t,
    const float* __restrict__ b2, const float* __restrict__ z,
    const int* __restrict__ meta, const int* __restrict__ perm,
    float* __restrict__ out) {
  __shared__ __align__(16) char smem[32768];
  __bf16* As = (__bf16*)smem;              // [128][64]
  __bf16* Bs = (__bf16*)(smem + 16384);    // [128][64]
  const int* offs = meta;
  int bid = blockIdx.x;
  int e = bid & 7;
  int r = bid >> 3;                         // 0..71
  int mt = r / 6, nt = r % 6;
  int off0 = offs[e];
  int cnt = offs[e + 1] - off0;
  if ((mt << 7) >= cnt) return;
  int row0 = off0 + (mt << 7);
  int cntRem = cnt - (mt << 7);
  if (cntRem > 128) cntRem = 128;
  int n0 = nt << 7;
  int tid = threadIdx.x, lane = tid & 63, wv = tid >> 6;
  int wr = wv >> 2, wc = wv & 3;
  int swz = ((lane & 7) ^ (lane >> 3)) << 3;

  const __bf16* srcA[2];
  const __bf16* srcB[2];
  #pragma unroll
  for (int i = 0; i < 2; ++i) {
    int row = ((wv * 2 + i) << 3) + (lane >> 3);
    int rA = row < cntRem ? row : cntRem - 1;
    srcA[i] = act + (size_t)(row0 + rA) * IDIM + swz;
    srcB[i] = w2t + ((size_t)e * HDIM + n0 + row) * IDIM + swz;
  }

  int rswz = (lane & 7) << 3;
  f32x4 acc[4][2] = {};

  for (int kk = 0; kk < IDIM / 64; ++kk) {
    #pragma unroll
    for (int i = 0; i < 2; ++i) {
      gload16(As + ((wv * 2 + i) << 9), srcA[i] + kk * 64);
      gload16(Bs + ((wv * 2 + i) << 9), srcB[i] + kk * 64);
    }
    __syncthreads();
    #pragma unroll
    for (int k2 = 0; k2 < 2; ++k2) {
      int kb = (k2 * 32 + ((lane >> 4) << 3)) ^ rswz;
      bf16x8 a[4], b[2];
      #pragma unroll
      for (int mi = 0; mi < 4; ++mi)
        a[mi] = *(const bf16x8*)&As[((wr * 64 + mi * 16 + (lane & 15)) << 6) + kb];
      #pragma unroll
      for (int ni = 0; ni < 2; ++ni)
        b[ni] = *(const bf16x8*)&Bs[((wc * 32 + ni * 16 + (lane & 15)) << 6) + kb];
      #pragma unroll
      for (int mi = 0; mi < 4; ++mi)
        #pragma unroll
        for (int ni = 0; ni < 2; ++ni)
          acc[mi][ni] = __builtin_amdgcn_mfma_f32_16x16x32_bf16(a[mi], b[ni], acc[mi][ni], 0, 0, 0);
    }
    __syncthreads();
  }

  float bb[2];
  #pragma unroll
  for (int ni = 0; ni < 2; ++ni)
    bb[ni] = b2[e * HDIM + n0 + wc * 32 + ni * 16 + (lane & 15)];

  #pragma unroll
  for (int mi = 0; mi < 4; ++mi) {
    int gr0 = wr * 64 + mi * 16 + ((lane >> 4) << 2);
    #pragma unroll
    for (int r2 = 0; r2 < 4; ++r2) {
      int g = gr0 + r2;
      if (g < cntRem) {
        int p = row0 + g;
        int tok = perm[p];
        #pragma unroll
        for (int ni = 0; ni < 2; ++ni) {
          int col = n0 + wc * 32 + ni * 16 + (lane & 15);
          out[(size_t)tok * HDIM + col] =
              z[(size_t)tok * HDIM + col] + acc[mi][ni][r2] + bb[ni];
        }
      }
    }
  }
}

extern "C" void kernel_launch(void* const* d_in, const int* in_sizes, int n_in,
                              void* d_out, int out_size, void* d_ws, size_t ws_size,
                              hipStream_t stream) {
  const float* z  = (const float*)d_in[0];
  const int*   lid = (const int*)d_in[1];
  const float* w1 = (const float*)d_in[2];
  const float* b1 = (const float*)d_in[3];
  const float* w2 = (const float*)d_in[4];
  const float* b2 = (const float*)d_in[5];
  float* out = (float*)d_out;
  char* ws = (char*)d_ws;

  int* meta = (int*)ws;                     // 9 ints
  int* perm = (int*)(ws + 2048);            // NTOK ints
  __bf16* w1t = (__bf16*)(ws + 2048 + 32768);
  __bf16* w2t = w1t + (size_t)LNUM * HDIM * IDIM;
  __bf16* act = w2t + (size_t)LNUM * HDIM * IDIM;

  prep_kernel<<<NB_SC + NB_W, 256, 0, stream>>>(lid, w1, meta, perm, w1t);
  gemm1_kernel<<<G1GRID + NB_W2, 512, 0, stream>>>(z, w1t, b1, meta, perm, act,
                                                   w2, w2t);
  gemm2_kernel<<<G2GRID, 512, 0, stream>>>(act, w2t, b2, z, meta, perm, out);
}